// Round 1
// baseline (294.233 us; speedup 1.0000x reference)
//
#include <hip/hip_runtime.h>
#include <math.h>

#define G     1000
#define B     32
#define NC    2048
#define NT    2048
#define BN    (B * NT)
#define LOG2E 1.4426950408889634f
#define LN2PI 1.8378770664093453f   // ln(2*pi)

#if __has_builtin(__builtin_amdgcn_exp2f)
#define EXP2F(x) __builtin_amdgcn_exp2f(x)
#else
#define EXP2F(x) exp2f(x)
#endif

// ---------------------------------------------------------------------------
// Kernel A: h[b,0,g] = sum_n exp(-(t_g - x_n)^2 / (2 ls_x^2))          (density)
//           h[b,1,g] = (sum_n w * y_n) / (density + 1e-8)              (rest)
// One wave per (b,g). 32000 waves -> 8000 blocks of 256.
// ---------------------------------------------------------------------------
__global__ __launch_bounds__(256) void k_smooth(
    const float* __restrict__ xc, const float* __restrict__ yc,
    const float* __restrict__ ls_x, float* __restrict__ h,
    float* __restrict__ loss_slot) {
  if (blockIdx.x == 0 && threadIdx.x == 0) *loss_slot = 0.f;  // stream-ordered zero for k_pred's atomics

  int gid  = blockIdx.x * 256 + threadIdx.x;
  int wid  = gid >> 6;
  int lane = threadIdx.x & 63;
  int b = wid / G, g = wid - b * G;

  float ls = ls_x[0];
  float c1 = -LOG2E / (2.f * ls * ls);          // exp(a) == exp2(a*log2e)
  float tg = -2.2f + (4.4f / 999.f) * (float)g;

  const float* xb = xc + b * NC;
  const float* yb = yc + b * NC;

  float s0 = 0.f, s1 = 0.f;
  #pragma unroll 8
  for (int n = lane; n < NC; n += 64) {         // exactly 32 iters per lane
    float d = tg - xb[n];
    float w = EXP2F(d * d * c1);
    s0 += w;
    s1 = fmaf(w, yb[n], s1);
  }
  #pragma unroll
  for (int m = 32; m; m >>= 1) {
    s0 += __shfl_xor(s0, m);
    s1 += __shfl_xor(s1, m);
  }
  if (lane == 0) {
    h[(b * 2 + 0) * G + g] = s0;
    h[(b * 2 + 1) * G + g] = s1 / (s0 + 1e-8f);
  }
}

// ---------------------------------------------------------------------------
// Kernel B: full conv chain 2->16->32->16->2 (k=5, SAME, cross-correlation)
// per (batch, 250-wide tile) block, halo 8, LDS ping-pong. Softplus fused.
// ---------------------------------------------------------------------------
#define TILE 250
#define HALO 8
#define EXT  266          // TILE + 2*HALO
#define STR  272          // LDS row stride

template <int CIN, int COUT>
__device__ __forceinline__ void conv_layer(const float (*in)[STR], float (*out)[STR],
                                           const float* __restrict__ w,
                                           const float* __restrict__ bias,
                                           int margin, int ts, int tid) {
  const int lo = margin, hi = EXT - margin;
  for (int idx = tid; idx < COUT * EXT; idx += 256) {
    int oc = idx / EXT, e = idx - oc * EXT;
    float v = 0.f;
    if (e >= lo && e < hi) {
      int gp = ts - HALO + e;
      if (gp >= 0 && gp < G) {                  // SAME zero-padding at global bounds
        float s = bias[oc];
        const float* wo = w + oc * CIN * 5;
        #pragma unroll
        for (int ic = 0; ic < CIN; ++ic)
          #pragma unroll
          for (int k = 0; k < 5; ++k)
            s = fmaf(in[ic][e - 2 + k], wo[ic * 5 + k], s);
        v = fmaxf(s, 0.f);                      // ReLU (layers 1..3 only use this path)
      }
    }
    out[oc][e] = v;
  }
}

__global__ __launch_bounds__(256) void k_conv(
    const float* __restrict__ h,
    const float* __restrict__ W1, const float* __restrict__ B1,
    const float* __restrict__ W2, const float* __restrict__ B2,
    const float* __restrict__ W3, const float* __restrict__ B3,
    const float* __restrict__ W4, const float* __restrict__ B4,
    float* __restrict__ yg) {
  __shared__ float bufA[32][STR];
  __shared__ float bufB[32][STR];
  __shared__ float sW1[160], sB1[16], sW2[2560], sB2[32],
                   sW3[2560], sB3[16], sW4[160], sB4[2];

  int tid  = threadIdx.x;
  int b    = blockIdx.x >> 2;
  int tile = blockIdx.x & 3;
  int ts   = tile * TILE;

  for (int i = tid; i < 160;  i += 256) sW1[i] = W1[i];
  for (int i = tid; i < 16;   i += 256) sB1[i] = B1[i];
  for (int i = tid; i < 2560; i += 256) sW2[i] = W2[i];
  for (int i = tid; i < 32;   i += 256) sB2[i] = B2[i];
  for (int i = tid; i < 2560; i += 256) sW3[i] = W3[i];
  for (int i = tid; i < 16;   i += 256) sB3[i] = B3[i];
  for (int i = tid; i < 160;  i += 256) sW4[i] = W4[i];
  for (int i = tid; i < 2;    i += 256) sB4[i] = B4[i];

  // stage input channels (with halo, zero outside [0,G))
  for (int i = tid; i < 2 * EXT; i += 256) {
    int c = i / EXT, e = i - c * EXT;
    int gp = ts - HALO + e;
    bufA[c][e] = (gp >= 0 && gp < G) ? h[(b * 2 + c) * G + gp] : 0.f;
  }
  __syncthreads();

  conv_layer<2, 16>(bufA, bufB, sW1, sB1, 2, ts, tid);
  __syncthreads();
  conv_layer<16, 32>(bufB, bufA, sW2, sB2, 4, ts, tid);
  __syncthreads();
  conv_layer<32, 16>(bufA, bufB, sW3, sB3, 6, ts, tid);
  __syncthreads();

  // Layer 4 (no ReLU): ch0 -> mu_grid, ch1 -> softplus -> sigma_grid
  for (int idx = tid; idx < 2 * TILE; idx += 256) {
    int oc = idx / TILE, p = idx - oc * TILE, e = p + HALO;
    float s = sB4[oc];
    const float* wo = sW4 + oc * 80;
    #pragma unroll
    for (int ic = 0; ic < 16; ++ic)
      #pragma unroll
      for (int k = 0; k < 5; ++k)
        s = fmaf(bufB[ic][e - 2 + k], wo[ic * 5 + k], s);
    int gp = ts + p;
    if (oc == 0) {
      yg[(b * 2 + 0) * G + gp] = s;
    } else {
      float sp = fmaxf(s, 0.f) + log1pf(__expf(-fabsf(s)));  // stable softplus
      yg[(b * 2 + 1) * G + gp] = sp;
    }
  }
}

// ---------------------------------------------------------------------------
// Kernel C: mu/sigma = sum_g exp(-(x_t - t_g)^2/(2 ls_rho^2)) * y_grid[c,g]
// + logp + loss. One wave per (b,t). 65536 waves -> 16384 blocks.
// out layout: [0,BN) mu | [BN,2BN) sigma | [2BN] loss
// ---------------------------------------------------------------------------
__global__ __launch_bounds__(256) void k_pred(
    const float* __restrict__ xt, const float* __restrict__ yt,
    const float* __restrict__ ls_rho, const float* __restrict__ yg,
    float* __restrict__ out) {
  __shared__ float part[4];
  int gid  = blockIdx.x * 256 + threadIdx.x;
  int wid  = gid >> 6;
  int lane = threadIdx.x & 63;
  int wib  = threadIdx.x >> 6;
  int b = wid >> 11, t = wid & (NT - 1);

  float ls = ls_rho[0];
  float c2 = -LOG2E / (2.f * ls * ls);
  float xv = xt[b * NT + t];
  const float* y0 = yg + (b * 2 + 0) * G;
  const float* y1 = yg + (b * 2 + 1) * G;

  float mu = 0.f, sg = 0.f;
  #pragma unroll 4
  for (int g = lane; g < G; g += 64) {
    float d = xv - (-2.2f + (4.4f / 999.f) * (float)g);
    float w = EXP2F(d * d * c2);
    mu = fmaf(w, y0[g], mu);
    sg = fmaf(w, y1[g], sg);
  }
  #pragma unroll
  for (int m = 32; m; m >>= 1) {
    mu += __shfl_xor(mu, m);
    sg += __shfl_xor(sg, m);
  }
  if (lane == 0) {
    out[b * NT + t]      = mu;
    out[BN + b * NT + t] = sg;
    float z  = (yt[b * NT + t] - mu) / sg;
    part[wib] = -0.5f * z * z - __logf(sg) - 0.5f * LN2PI;
  }
  __syncthreads();
  if (threadIdx.x == 0) {
    float s = part[0] + part[1] + part[2] + part[3];
    atomicAdd(out + 2 * BN, -s * (1.f / (float)NT));
  }
}

extern "C" void kernel_launch(void* const* d_in, const int* in_sizes, int n_in,
                              void* d_out, int out_size, void* d_ws, size_t ws_size,
                              hipStream_t stream) {
  const float* xc  = (const float*)d_in[0];
  const float* yc  = (const float*)d_in[1];
  const float* xt  = (const float*)d_in[2];
  const float* yt  = (const float*)d_in[3];
  const float* lsx = (const float*)d_in[4];
  const float* lsr = (const float*)d_in[5];
  const float* W1  = (const float*)d_in[6];  const float* b1 = (const float*)d_in[7];
  const float* W2  = (const float*)d_in[8];  const float* b2 = (const float*)d_in[9];
  const float* W3  = (const float*)d_in[10]; const float* b3 = (const float*)d_in[11];
  const float* W4  = (const float*)d_in[12]; const float* b4 = (const float*)d_in[13];

  float* out = (float*)d_out;
  float* h   = (float*)d_ws;        // B*2*G
  float* yg  = h + B * 2 * G;       // B*2*G

  k_smooth<<<(B * G) / 4, 256, 0, stream>>>(xc, yc, lsx, h, out + 2 * BN);
  k_conv<<<B * 4, 256, 0, stream>>>(h, W1, b1, W2, b2, W3, b3, W4, b4, yg);
  k_pred<<<BN / 4, 256, 0, stream>>>(xt, yt, lsr, yg, out);
}

// Round 2
// 108.087 us; speedup vs baseline: 2.7222x; 2.7222x over previous
//
#include <hip/hip_runtime.h>
#include <math.h>

#define G     1000
#define B     32
#define NC    2048
#define NT    2048
#define BN    (B * NT)
#define LOG2E 1.4426950408889634f
#define LN2PI 1.8378770664093453f   // ln(2*pi)

#if __has_builtin(__builtin_amdgcn_exp2f)
#define EXP2F(x) __builtin_amdgcn_exp2f(x)
#else
#define EXP2F(x) exp2f(x)
#endif

// ---------------------------------------------------------------------------
// Kernel A v2: h[b,0,g] = sum_n exp(-(t_g-x_n)^2/(2 ls^2)); h[b,1,g] = wsum/(den+1e-8)
// Thread-per-g, operands staged in LDS, read as wave-broadcast.
// block = 512 (256 g-slots x 2 n-halves); grid = B*4 g-tiles.
// w = exp2(-(s*t - s*x)^2), s = sqrt(log2e/(2 ls^2)) folded at stage time.
// ---------------------------------------------------------------------------
__global__ __launch_bounds__(512) void k_smooth(
    const float* __restrict__ xc, const float* __restrict__ yc,
    const float* __restrict__ ls_x, float* __restrict__ h,
    float* __restrict__ loss_slot) {
  __shared__ float sxy[NC * 2];           // interleaved {s*x_n, y_n}, 16KB
  __shared__ float pm[512], ps[512];
  if (blockIdx.x == 0 && threadIdx.x == 0) *loss_slot = 0.f;  // stream-ordered zero

  int tid = threadIdx.x;
  int b = blockIdx.x >> 2, tile = blockIdx.x & 3;
  float ls = ls_x[0];
  float s  = sqrtf(0.5f * LOG2E) / ls;

  const float* xb = xc + b * NC;
  const float* yb = yc + b * NC;
  for (int n = tid; n < NC; n += 512) {
    sxy[2 * n]     = s * xb[n];
    sxy[2 * n + 1] = yb[n];
  }
  __syncthreads();

  int gl = tid & 255, half = tid >> 8;
  int g  = tile * 256 + gl;
  float tgp = s * (-2.2f + (4.4f / 999.f) * (float)g);

  float s0 = 0.f, s1 = 0.f;
  const float2* p = ((const float2*)sxy) + half * (NC / 2);
  #pragma unroll 8
  for (int n = 0; n < NC / 2; ++n) {      // 1024 iters, ds_read_b64 broadcast
    float2 v = p[n];
    float d = tgp - v.x;
    float w = EXP2F(-(d * d));
    s0 += w;
    s1 = fmaf(w, v.y, s1);
  }
  pm[tid] = s0; ps[tid] = s1;
  __syncthreads();

  if (half == 0 && g < G) {
    float d0 = s0 + pm[tid + 256];
    float d1 = s1 + ps[tid + 256];
    h[(b * 2 + 0) * G + g] = d0;
    h[(b * 2 + 1) * G + g] = d1 / (d0 + 1e-8f);
  }
}

// ---------------------------------------------------------------------------
// Kernel B: conv chain 2->16->32->16->2 (k=5, SAME), LDS ping-pong (unchanged)
// ---------------------------------------------------------------------------
#define TILE 250
#define HALO 8
#define EXT  266
#define STR  272

template <int CIN, int COUT>
__device__ __forceinline__ void conv_layer(const float (*in)[STR], float (*out)[STR],
                                           const float* __restrict__ w,
                                           const float* __restrict__ bias,
                                           int margin, int ts, int tid) {
  const int lo = margin, hi = EXT - margin;
  for (int idx = tid; idx < COUT * EXT; idx += 256) {
    int oc = idx / EXT, e = idx - oc * EXT;
    float v = 0.f;
    if (e >= lo && e < hi) {
      int gp = ts - HALO + e;
      if (gp >= 0 && gp < G) {
        float s = bias[oc];
        const float* wo = w + oc * CIN * 5;
        #pragma unroll
        for (int ic = 0; ic < CIN; ++ic)
          #pragma unroll
          for (int k = 0; k < 5; ++k)
            s = fmaf(in[ic][e - 2 + k], wo[ic * 5 + k], s);
        v = fmaxf(s, 0.f);
      }
    }
    out[oc][e] = v;
  }
}

__global__ __launch_bounds__(256) void k_conv(
    const float* __restrict__ h,
    const float* __restrict__ W1, const float* __restrict__ B1,
    const float* __restrict__ W2, const float* __restrict__ B2,
    const float* __restrict__ W3, const float* __restrict__ B3,
    const float* __restrict__ W4, const float* __restrict__ B4,
    float* __restrict__ yg) {
  __shared__ float bufA[32][STR];
  __shared__ float bufB[32][STR];
  __shared__ float sW1[160], sB1[16], sW2[2560], sB2[32],
                   sW3[2560], sB3[16], sW4[160], sB4[2];

  int tid  = threadIdx.x;
  int b    = blockIdx.x >> 2;
  int tile = blockIdx.x & 3;
  int ts   = tile * TILE;

  for (int i = tid; i < 160;  i += 256) sW1[i] = W1[i];
  for (int i = tid; i < 16;   i += 256) sB1[i] = B1[i];
  for (int i = tid; i < 2560; i += 256) sW2[i] = W2[i];
  for (int i = tid; i < 32;   i += 256) sB2[i] = B2[i];
  for (int i = tid; i < 2560; i += 256) sW3[i] = W3[i];
  for (int i = tid; i < 16;   i += 256) sB3[i] = B3[i];
  for (int i = tid; i < 160;  i += 256) sW4[i] = W4[i];
  for (int i = tid; i < 2;    i += 256) sB4[i] = B4[i];

  for (int i = tid; i < 2 * EXT; i += 256) {
    int c = i / EXT, e = i - c * EXT;
    int gp = ts - HALO + e;
    bufA[c][e] = (gp >= 0 && gp < G) ? h[(b * 2 + c) * G + gp] : 0.f;
  }
  __syncthreads();

  conv_layer<2, 16>(bufA, bufB, sW1, sB1, 2, ts, tid);
  __syncthreads();
  conv_layer<16, 32>(bufB, bufA, sW2, sB2, 4, ts, tid);
  __syncthreads();
  conv_layer<32, 16>(bufA, bufB, sW3, sB3, 6, ts, tid);
  __syncthreads();

  for (int idx = tid; idx < 2 * TILE; idx += 256) {
    int oc = idx / TILE, p = idx - oc * TILE, e = p + HALO;
    float s = sB4[oc];
    const float* wo = sW4 + oc * 80;
    #pragma unroll
    for (int ic = 0; ic < 16; ++ic)
      #pragma unroll
      for (int k = 0; k < 5; ++k)
        s = fmaf(bufB[ic][e - 2 + k], wo[ic * 5 + k], s);
    int gp = ts + p;
    if (oc == 0) {
      yg[(b * 2 + 0) * G + gp] = s;
    } else {
      float sp = fmaxf(s, 0.f) + log1pf(__expf(-fabsf(s)));
      yg[(b * 2 + 1) * G + gp] = sp;
    }
  }
}

// ---------------------------------------------------------------------------
// Kernel C v2: mu/sigma/logp/loss. Thread-per-t, y_grid + t' staged as float4
// in LDS (ds_read_b128 broadcast). block = 512 (256 t x 2 g-halves);
// grid = B*8 t-tiles. out: [0,BN) mu | [BN,2BN) sigma | [2BN] loss
// ---------------------------------------------------------------------------
__global__ __launch_bounds__(512) void k_pred(
    const float* __restrict__ xt, const float* __restrict__ yt,
    const float* __restrict__ ls_rho, const float* __restrict__ yg,
    float* __restrict__ out) {
  __shared__ float4 sp[G];                // {s*t_g, y0_g, y1_g, 0}, 16KB
  __shared__ float pm[512], ps[512];
  __shared__ float red[8];

  int tid = threadIdx.x;
  int b = blockIdx.x >> 3, tile = blockIdx.x & 7;
  float ls = ls_rho[0];
  float s  = sqrtf(0.5f * LOG2E) / ls;

  const float* y0 = yg + (b * 2 + 0) * G;
  const float* y1 = yg + (b * 2 + 1) * G;
  for (int g = tid; g < G; g += 512) {
    float tg = -2.2f + (4.4f / 999.f) * (float)g;
    sp[g] = make_float4(s * tg, y0[g], y1[g], 0.f);
  }
  __syncthreads();

  int tl = tid & 255, half = tid >> 8;
  int t  = tile * 256 + tl;
  float xv = s * xt[b * NT + t];

  float mu = 0.f, sg = 0.f;
  const float4* p = sp + half * (G / 2);
  #pragma unroll 4
  for (int n = 0; n < G / 2; ++n) {       // 500 iters, ds_read_b128 broadcast
    float4 v = p[n];
    float d = xv - v.x;
    float w = EXP2F(-(d * d));
    mu = fmaf(w, v.y, mu);
    sg = fmaf(w, v.z, sg);
  }
  pm[tid] = mu; ps[tid] = sg;
  __syncthreads();

  float lp = 0.f;
  if (half == 0) {
    mu += pm[tid + 256];
    sg += ps[tid + 256];
    out[b * NT + t]      = mu;
    out[BN + b * NT + t] = sg;
    float z = (yt[b * NT + t] - mu) / sg;
    lp = -0.5f * z * z - __logf(sg) - 0.5f * LN2PI;
  }
  #pragma unroll
  for (int m = 32; m; m >>= 1) lp += __shfl_xor(lp, m);
  int wib = tid >> 6, lane = tid & 63;
  if (lane == 0) red[wib] = lp;
  __syncthreads();
  if (tid == 0) {
    float tot = 0.f;
    #pragma unroll
    for (int i = 0; i < 8; ++i) tot += red[i];
    atomicAdd(out + 2 * BN, -tot * (1.f / (float)NT));
  }
}

extern "C" void kernel_launch(void* const* d_in, const int* in_sizes, int n_in,
                              void* d_out, int out_size, void* d_ws, size_t ws_size,
                              hipStream_t stream) {
  const float* xc  = (const float*)d_in[0];
  const float* yc  = (const float*)d_in[1];
  const float* xt  = (const float*)d_in[2];
  const float* yt  = (const float*)d_in[3];
  const float* lsx = (const float*)d_in[4];
  const float* lsr = (const float*)d_in[5];
  const float* W1  = (const float*)d_in[6];  const float* b1 = (const float*)d_in[7];
  const float* W2  = (const float*)d_in[8];  const float* b2 = (const float*)d_in[9];
  const float* W3  = (const float*)d_in[10]; const float* b3 = (const float*)d_in[11];
  const float* W4  = (const float*)d_in[12]; const float* b4 = (const float*)d_in[13];

  float* out = (float*)d_out;
  float* h   = (float*)d_ws;        // B*2*G
  float* yg  = h + B * 2 * G;       // B*2*G

  k_smooth<<<B * 4, 512, 0, stream>>>(xc, yc, lsx, h, out + 2 * BN);
  k_conv<<<B * 4, 256, 0, stream>>>(h, W1, b1, W2, b2, W3, b3, W4, b4, yg);
  k_pred<<<B * 8, 512, 0, stream>>>(xt, yt, lsr, yg, out);
}

// Round 3
// 58.009 us; speedup vs baseline: 5.0722x; 1.8633x over previous
//
#include <hip/hip_runtime.h>
#include <math.h>

#define G     1000
#define B     32
#define NC    2048
#define NT    2048
#define BN    (B * NT)
#define LOG2E 1.4426950408889634f
#define LN2PI 1.8378770664093453f   // ln(2*pi)

#if __has_builtin(__builtin_amdgcn_exp2f)
#define EXP2F(x) __builtin_amdgcn_exp2f(x)
#else
#define EXP2F(x) exp2f(x)
#endif

// ---------------------------------------------------------------------------
// Kernel A v3: grid (16 g-tiles x B), block 512 = 64 g x 8 n-slices.
// ---------------------------------------------------------------------------
__global__ __launch_bounds__(512) void k_smooth(
    const float* __restrict__ xc, const float* __restrict__ yc,
    const float* __restrict__ ls_x, float* __restrict__ h,
    float* __restrict__ loss_slot) {
  __shared__ float sxy[NC * 2];           // {s*x_n, y_n} interleaved, 16KB
  __shared__ float pm[512], ps[512];
  if (blockIdx.x == 0 && blockIdx.y == 0 && threadIdx.x == 0) *loss_slot = 0.f;

  int tid = threadIdx.x;
  int b = blockIdx.y, tile = blockIdx.x;
  float ls = ls_x[0];
  float s  = sqrtf(0.5f * LOG2E) / ls;    // w = exp2(-(s*t - s*x)^2)

  const float* xb = xc + b * NC;
  const float* yb = yc + b * NC;
  for (int n = tid; n < NC; n += 512) {
    sxy[2 * n]     = s * xb[n];
    sxy[2 * n + 1] = yb[n];
  }
  __syncthreads();

  int gl = tid & 63, q = tid >> 6;        // 64 g-slots x 8 n-slices
  int g  = tile * 64 + gl;
  float tgp = s * (-2.2f + (4.4f / 999.f) * (float)g);

  float s0 = 0.f, s1 = 0.f;
  const float4* p = ((const float4*)sxy) + q * (NC / 16);   // 128 f4 (2 pairs each)
  #pragma unroll 4
  for (int i = 0; i < NC / 16; ++i) {
    float4 v = p[i];
    float d0 = tgp - v.x; float w0 = EXP2F(-(d0 * d0));
    float d1 = tgp - v.z; float w1 = EXP2F(-(d1 * d1));
    s0 += w0; s1 = fmaf(w0, v.y, s1);
    s0 += w1; s1 = fmaf(w1, v.w, s1);
  }
  pm[tid] = s0; ps[tid] = s1;
  __syncthreads();

  if (q == 0 && g < G) {
    float d0 = s0, d1 = s1;
    #pragma unroll
    for (int k = 1; k < 8; ++k) { d0 += pm[tid + 64 * k]; d1 += ps[tid + 64 * k]; }
    h[(b * 2 + 0) * G + g] = d0;
    h[(b * 2 + 1) * G + g] = d1 / (d0 + 1e-8f);
  }
}

// ---------------------------------------------------------------------------
// Kernel B v3: conv chain, register-blocked. TILE=80, logical e in [0,96),
// buffer col = e+4 (pads at cols 0..3 / 100..103), stride 108.
// Thread -> (oc = tid%COUT, sub = tid/COUT), POS consecutive positions.
// Weights in LDS transposed [(ic*5+k)][oc] -> lane-consecutive = bank-perfect.
// Validity chain: L1 [0,96) -> L2 [2,94) -> L3 [4,92) -> L4 [6,90) ⊇ [8,88).
// ---------------------------------------------------------------------------
#define TILE  80
#define HALO  8
#define EXTW  96
#define CSTR  108
#define NTILE 13   // 13*80 = 1040 >= 1000

template <int CIN, int COUT, int POS, int NG>
__device__ __forceinline__ void conv_layer(
    const float (*in)[CSTR], float (*out)[CSTR],
    const float* __restrict__ wt, const float* __restrict__ bias, int tid) {
  if (tid < COUT * 8) {                   // zero pad cols of out
    int oc = tid >> 3, j = tid & 7;
    out[oc][(j & 3) + (j >> 2) * 100] = 0.f;
  }
  int oc  = tid % COUT;
  int sub = tid / COUT;
  int e0  = sub * POS;                    // e0 % 4 == 0 always (POS in {8,12})
  if (e0 < EXTW) {
    float acc[POS];
    float bb = bias[oc];
    #pragma unroll
    for (int p = 0; p < POS; ++p) acc[p] = bb;
    for (int ic = 0; ic < CIN; ++ic) {
      float v[NG * 4];                    // logical e0-4 .. e0-4+4*NG
      #pragma unroll
      for (int r = 0; r < NG; ++r) {
        float4 t4 = *(const float4*)&in[ic][e0 + 4 * r];
        v[4 * r] = t4.x; v[4 * r + 1] = t4.y; v[4 * r + 2] = t4.z; v[4 * r + 3] = t4.w;
      }
      float w[5];
      #pragma unroll
      for (int k = 0; k < 5; ++k) w[k] = wt[(ic * 5 + k) * COUT + oc];
      #pragma unroll
      for (int p = 0; p < POS; ++p)
        #pragma unroll
        for (int k = 0; k < 5; ++k)
          acc[p] = fmaf(v[p + k + 2], w[k], acc[p]);   // logical e0+p-2+k
    }
    #pragma unroll
    for (int p = 0; p < POS; ++p) acc[p] = fmaxf(acc[p], 0.f);
    #pragma unroll
    for (int r = 0; r < POS / 4; ++r) {
      float4 o = make_float4(acc[4 * r], acc[4 * r + 1], acc[4 * r + 2], acc[4 * r + 3]);
      *(float4*)&out[oc][e0 + 4 + 4 * r] = o;
    }
  }
}

__global__ __launch_bounds__(256) void k_conv(
    const float* __restrict__ h,
    const float* __restrict__ W1, const float* __restrict__ Bs1,
    const float* __restrict__ W2, const float* __restrict__ Bs2,
    const float* __restrict__ W3, const float* __restrict__ Bs3,
    const float* __restrict__ W4, const float* __restrict__ Bs4,
    float* __restrict__ yg) {
  __shared__ float bufA[32][CSTR], bufB[32][CSTR];
  __shared__ float wt1[160], wt2[2560], wt3[2560], wt4[160];
  __shared__ float sB1[16], sB2[32], sB3[16], sB4[2];

  int tid  = threadIdx.x;
  int tile = blockIdx.x, b = blockIdx.y;
  int ts   = tile * TILE;

  // transposed weights: wt[(ic*5+k)*COUT + oc] = W[oc*(CIN*5) + (ic*5+k)]
  for (int i = tid; i < 160;  i += 256) wt1[i] = W1[(i & 15) * 10  + (i >> 4)];
  for (int i = tid; i < 2560; i += 256) wt2[i] = W2[(i & 31) * 80  + (i >> 5)];
  for (int i = tid; i < 2560; i += 256) wt3[i] = W3[(i & 15) * 160 + (i >> 4)];
  for (int i = tid; i < 160;  i += 256) wt4[i] = W4[(i & 1)  * 80  + (i >> 1)];
  if (tid < 16)       sB1[tid]      = Bs1[tid];
  else if (tid < 48)  sB2[tid - 16] = Bs2[tid - 16];
  else if (tid < 64)  sB3[tid - 48] = Bs3[tid - 48];
  else if (tid < 66)  sB4[tid - 64] = Bs4[tid - 64];

  // stage inputs: cols [0,108) = logical [-4,104) = global [ts-12, ts+92)
  for (int i = tid; i < 2 * CSTR; i += 256) {
    int c = i >= CSTR, col = i - c * CSTR;
    int g = ts + col - 12;
    bufA[c][col] = (g >= 0 && g < G) ? h[(b * 2 + c) * G + g] : 0.f;
  }
  __syncthreads();

  conv_layer<2, 16, 8, 4>(bufA, bufB, wt1, sB1, tid);
  __syncthreads();
  conv_layer<16, 32, 12, 5>(bufB, bufA, wt2, sB2, tid);
  __syncthreads();
  conv_layer<32, 16, 8, 4>(bufA, bufB, wt3, sB3, tid);
  __syncthreads();

  // Layer 4: oc = tid&1, sub = tid>>1 covers 80 outputs; softplus on ch1
  {
    int oc = tid & 1, sub = tid >> 1;
    if (sub < TILE) {
      int gp = ts + sub;
      if (gp < G) {
        int e = HALO + sub;             // logical position
        float sacc = sB4[oc];
        #pragma unroll
        for (int ic = 0; ic < 16; ++ic)
          #pragma unroll
          for (int k = 0; k < 5; ++k)
            sacc = fmaf(bufB[ic][e + 2 + k], wt4[(ic * 5 + k) * 2 + oc], sacc);
        if (oc == 0) {
          yg[(b * 2 + 0) * G + gp] = sacc;
        } else {
          float sp_ = fmaxf(sacc, 0.f) + log1pf(__expf(-fabsf(sacc)));
          yg[(b * 2 + 1) * G + gp] = sp_;
        }
      }
    }
  }
}

// ---------------------------------------------------------------------------
// Kernel C v3: grid (16 t-tiles x B), block 512 = 128 t x 4 g-quarters.
// out: [0,BN) mu | [BN,2BN) sigma | [2BN] loss
// ---------------------------------------------------------------------------
__global__ __launch_bounds__(512) void k_pred(
    const float* __restrict__ xt, const float* __restrict__ yt,
    const float* __restrict__ ls_rho, const float* __restrict__ yg,
    float* __restrict__ out) {
  __shared__ float4 sp[G];                // {s*t_g, y0_g, y1_g, 0}, 16KB
  __shared__ float pm[512], ps[512];
  __shared__ float red[8];

  int tid = threadIdx.x;
  int b = blockIdx.y, tile = blockIdx.x;
  float ls = ls_rho[0];
  float s  = sqrtf(0.5f * LOG2E) / ls;

  const float* y0 = yg + (b * 2 + 0) * G;
  const float* y1 = yg + (b * 2 + 1) * G;
  for (int g = tid; g < G; g += 512) {
    float tg = -2.2f + (4.4f / 999.f) * (float)g;
    sp[g] = make_float4(s * tg, y0[g], y1[g], 0.f);
  }
  __syncthreads();

  int tl = tid & 127, q = tid >> 7;       // 128 t x 4 quarters (250 g each)
  int t  = tile * 128 + tl;
  float xv = s * xt[b * NT + t];

  float mu = 0.f, sg = 0.f;
  const float4* p = sp + q * 250;
  #pragma unroll 2
  for (int i = 0; i < 250; ++i) {
    float4 v = p[i];
    float d = xv - v.x;
    float w = EXP2F(-(d * d));
    mu = fmaf(w, v.y, mu);
    sg = fmaf(w, v.z, sg);
  }
  pm[tid] = mu; ps[tid] = sg;
  __syncthreads();

  float lp = 0.f;
  if (q == 0) {
    #pragma unroll
    for (int k = 1; k < 4; ++k) { mu += pm[tid + 128 * k]; sg += ps[tid + 128 * k]; }
    out[b * NT + t]      = mu;
    out[BN + b * NT + t] = sg;
    float z = (yt[b * NT + t] - mu) / sg;
    lp = -0.5f * z * z - __logf(sg) - 0.5f * LN2PI;
  }
  #pragma unroll
  for (int m = 32; m; m >>= 1) lp += __shfl_xor(lp, m);
  if ((tid & 63) == 0) red[tid >> 6] = lp;
  __syncthreads();
  if (tid == 0) {
    float tot = 0.f;
    #pragma unroll
    for (int i = 0; i < 8; ++i) tot += red[i];
    atomicAdd(out + 2 * BN, -tot * (1.f / (float)NT));
  }
}

extern "C" void kernel_launch(void* const* d_in, const int* in_sizes, int n_in,
                              void* d_out, int out_size, void* d_ws, size_t ws_size,
                              hipStream_t stream) {
  const float* xc  = (const float*)d_in[0];
  const float* yc  = (const float*)d_in[1];
  const float* xt  = (const float*)d_in[2];
  const float* yt  = (const float*)d_in[3];
  const float* lsx = (const float*)d_in[4];
  const float* lsr = (const float*)d_in[5];
  const float* W1  = (const float*)d_in[6];  const float* b1 = (const float*)d_in[7];
  const float* W2  = (const float*)d_in[8];  const float* b2 = (const float*)d_in[9];
  const float* W3  = (const float*)d_in[10]; const float* b3 = (const float*)d_in[11];
  const float* W4  = (const float*)d_in[12]; const float* b4 = (const float*)d_in[13];

  float* out = (float*)d_out;
  float* h   = (float*)d_ws;        // B*2*G
  float* yg  = h + B * 2 * G;       // B*2*G

  k_smooth<<<dim3(16, B), 512, 0, stream>>>(xc, yc, lsx, h, out + 2 * BN);
  k_conv<<<dim3(NTILE, B), 256, 0, stream>>>(h, W1, b1, W2, b2, W3, b3, W4, b4, yg);
  k_pred<<<dim3(16, B), 512, 0, stream>>>(xt, yt, lsr, yg, out);
}

// Round 4
// 50.428 us; speedup vs baseline: 5.8347x; 1.1503x over previous
//
#include <hip/hip_runtime.h>
#include <math.h>

#define G     1000
#define B     32
#define NC    2048
#define NT    2048
#define BN    (B * NT)
#define LOG2E 1.4426950408889634f
#define LN2PI 1.8378770664093453f   // ln(2*pi)

#if __has_builtin(__builtin_amdgcn_exp2f)
#define EXP2F(x) __builtin_amdgcn_exp2f(x)
#else
#define EXP2F(x) exp2f(x)
#endif

// ---------------------------------------------------------------------------
// Kernel A v3 (unchanged from r3): grid (16 g-tiles x B), block 512 = 64g x 8n.
// ---------------------------------------------------------------------------
__global__ __launch_bounds__(512) void k_smooth(
    const float* __restrict__ xc, const float* __restrict__ yc,
    const float* __restrict__ ls_x, float* __restrict__ h,
    float* __restrict__ loss_slot) {
  __shared__ float sxy[NC * 2];           // {s*x_n, y_n} interleaved, 16KB
  __shared__ float pm[512], ps[512];
  if (blockIdx.x == 0 && blockIdx.y == 0 && threadIdx.x == 0) *loss_slot = 0.f;

  int tid = threadIdx.x;
  int b = blockIdx.y, tile = blockIdx.x;
  float ls = ls_x[0];
  float s  = sqrtf(0.5f * LOG2E) / ls;    // w = exp2(-(s*t - s*x)^2)

  const float* xb = xc + b * NC;
  const float* yb = yc + b * NC;
  for (int n = tid; n < NC; n += 512) {
    sxy[2 * n]     = s * xb[n];
    sxy[2 * n + 1] = yb[n];
  }
  __syncthreads();

  int gl = tid & 63, q = tid >> 6;        // 64 g-slots x 8 n-slices
  int g  = tile * 64 + gl;
  float tgp = s * (-2.2f + (4.4f / 999.f) * (float)g);

  float s0 = 0.f, s1 = 0.f;
  const float4* p = ((const float4*)sxy) + q * (NC / 16);
  #pragma unroll 4
  for (int i = 0; i < NC / 16; ++i) {
    float4 v = p[i];
    float d0 = tgp - v.x; float w0 = EXP2F(-(d0 * d0));
    float d1 = tgp - v.z; float w1 = EXP2F(-(d1 * d1));
    s0 += w0; s1 = fmaf(w0, v.y, s1);
    s0 += w1; s1 = fmaf(w1, v.w, s1);
  }
  pm[tid] = s0; ps[tid] = s1;
  __syncthreads();

  if (q == 0 && g < G) {
    float d0 = s0, d1 = s1;
    #pragma unroll
    for (int k = 1; k < 8; ++k) { d0 += pm[tid + 64 * k]; d1 += ps[tid + 64 * k]; }
    h[(b * 2 + 0) * G + g] = d0;
    h[(b * 2 + 1) * G + g] = d1 / (d0 + 1e-8f);
  }
}

// ---------------------------------------------------------------------------
// Kernel B v3 (unchanged from r3): register-blocked conv chain, TILE=80.
// Validity chain: L1 [0,96) -> L2 [2,94) -> L3 [4,92) -> L4 [6,90) ⊇ [8,88).
// ---------------------------------------------------------------------------
#define TILE  80
#define HALO  8
#define EXTW  96
#define CSTR  108
#define NTILE 13   // 13*80 = 1040 >= 1000

template <int CIN, int COUT, int POS, int NG>
__device__ __forceinline__ void conv_layer(
    const float (*in)[CSTR], float (*out)[CSTR],
    const float* __restrict__ wt, const float* __restrict__ bias, int tid) {
  if (tid < COUT * 8) {                   // zero pad cols of out
    int oc = tid >> 3, j = tid & 7;
    out[oc][(j & 3) + (j >> 2) * 100] = 0.f;
  }
  int oc  = tid % COUT;
  int sub = tid / COUT;
  int e0  = sub * POS;
  if (e0 < EXTW) {
    float acc[POS];
    float bb = bias[oc];
    #pragma unroll
    for (int p = 0; p < POS; ++p) acc[p] = bb;
    for (int ic = 0; ic < CIN; ++ic) {
      float v[NG * 4];
      #pragma unroll
      for (int r = 0; r < NG; ++r) {
        float4 t4 = *(const float4*)&in[ic][e0 + 4 * r];
        v[4 * r] = t4.x; v[4 * r + 1] = t4.y; v[4 * r + 2] = t4.z; v[4 * r + 3] = t4.w;
      }
      float w[5];
      #pragma unroll
      for (int k = 0; k < 5; ++k) w[k] = wt[(ic * 5 + k) * COUT + oc];
      #pragma unroll
      for (int p = 0; p < POS; ++p)
        #pragma unroll
        for (int k = 0; k < 5; ++k)
          acc[p] = fmaf(v[p + k + 2], w[k], acc[p]);
    }
    #pragma unroll
    for (int p = 0; p < POS; ++p) acc[p] = fmaxf(acc[p], 0.f);
    #pragma unroll
    for (int r = 0; r < POS / 4; ++r) {
      float4 o = make_float4(acc[4 * r], acc[4 * r + 1], acc[4 * r + 2], acc[4 * r + 3]);
      *(float4*)&out[oc][e0 + 4 + 4 * r] = o;
    }
  }
}

__global__ __launch_bounds__(256) void k_conv(
    const float* __restrict__ h,
    const float* __restrict__ W1, const float* __restrict__ Bs1,
    const float* __restrict__ W2, const float* __restrict__ Bs2,
    const float* __restrict__ W3, const float* __restrict__ Bs3,
    const float* __restrict__ W4, const float* __restrict__ Bs4,
    float* __restrict__ yg) {
  __shared__ float bufA[32][CSTR], bufB[32][CSTR];
  __shared__ float wt1[160], wt2[2560], wt3[2560], wt4[160];
  __shared__ float sB1[16], sB2[32], sB3[16], sB4[2];

  int tid  = threadIdx.x;
  int tile = blockIdx.x, b = blockIdx.y;
  int ts   = tile * TILE;

  for (int i = tid; i < 160;  i += 256) wt1[i] = W1[(i & 15) * 10  + (i >> 4)];
  for (int i = tid; i < 2560; i += 256) wt2[i] = W2[(i & 31) * 80  + (i >> 5)];
  for (int i = tid; i < 2560; i += 256) wt3[i] = W3[(i & 15) * 160 + (i >> 4)];
  for (int i = tid; i < 160;  i += 256) wt4[i] = W4[(i & 1)  * 80  + (i >> 1)];
  if (tid < 16)       sB1[tid]      = Bs1[tid];
  else if (tid < 48)  sB2[tid - 16] = Bs2[tid - 16];
  else if (tid < 64)  sB3[tid - 48] = Bs3[tid - 48];
  else if (tid < 66)  sB4[tid - 64] = Bs4[tid - 64];

  for (int i = tid; i < 2 * CSTR; i += 256) {
    int c = i >= CSTR, col = i - c * CSTR;
    int g = ts + col - 12;
    bufA[c][col] = (g >= 0 && g < G) ? h[(b * 2 + c) * G + g] : 0.f;
  }
  __syncthreads();

  conv_layer<2, 16, 8, 4>(bufA, bufB, wt1, sB1, tid);
  __syncthreads();
  conv_layer<16, 32, 12, 5>(bufB, bufA, wt2, sB2, tid);
  __syncthreads();
  conv_layer<32, 16, 8, 4>(bufA, bufB, wt3, sB3, tid);
  __syncthreads();

  {
    int oc = tid & 1, sub = tid >> 1;
    if (sub < TILE) {
      int gp = ts + sub;
      if (gp < G) {
        int e = HALO + sub;
        float sacc = sB4[oc];
        #pragma unroll
        for (int ic = 0; ic < 16; ++ic)
          #pragma unroll
          for (int k = 0; k < 5; ++k)
            sacc = fmaf(bufB[ic][e + 2 + k], wt4[(ic * 5 + k) * 2 + oc], sacc);
        if (oc == 0) {
          yg[(b * 2 + 0) * G + gp] = sacc;
        } else {
          float sp_ = fmaxf(sacc, 0.f) + log1pf(__expf(-fabsf(sacc)));
          yg[(b * 2 + 1) * G + gp] = sp_;
        }
      }
    }
  }
}

// ---------------------------------------------------------------------------
// Kernel C v4: Gaussian recurrence — no exp in the loop.
//   w_g = 2^(-(u - v_g)^2), v_g = s*t_g equally spaced (step delta)
//   w_{g+1} = w_g * q_g ; q_{g+1} = q_g * r ; r = 2^(-2 delta^2)
// Track W = 2^64 * w (a^2 <= ~130 for |x|<=4.5sigma -> W in [2^-66, 2^64]),
// rescale by 2^-64 after the slice reduction. 4 g-slices of 250 per t.
// ---------------------------------------------------------------------------
__global__ __launch_bounds__(512) void k_pred(
    const float* __restrict__ xt, const float* __restrict__ yt,
    const float* __restrict__ ls_rho, const float* __restrict__ yg,
    float* __restrict__ out) {
  __shared__ float2 sp[G];                // {y0_g, y1_g}, 8KB
  __shared__ float pm[512], ps[512];
  __shared__ float red[8];

  int tid = threadIdx.x;
  int b = blockIdx.y, tile = blockIdx.x;
  float ls = ls_rho[0];
  float s  = sqrtf(0.5f * LOG2E) / ls;
  float dl = s * (4.4f / 999.f);          // delta

  const float* y0 = yg + (b * 2 + 0) * G;
  const float* y1 = yg + (b * 2 + 1) * G;
  for (int g = tid; g < G; g += 512) sp[g] = make_float2(y0[g], y1[g]);
  __syncthreads();

  int tl = tid & 127, qi = tid >> 7;      // 128 t x 4 slices (250 g each)
  int t  = tile * 128 + tl;
  float u  = s * xt[b * NT + t];
  float a  = u + 2.2f * s - dl * (float)(qi * 250);  // u - v_{g0}
  float W  = EXP2F(64.f - a * a);
  float q  = EXP2F(dl * (a + a) - dl * dl);
  float r  = EXP2F(-2.f * dl * dl);

  float mu = 0.f, sg = 0.f;
  const float2* p = sp + qi * 250;
  #pragma unroll 2
  for (int i = 0; i < 250; ++i) {
    float2 v = p[i];
    mu = fmaf(W, v.x, mu);
    sg = fmaf(W, v.y, sg);
    W *= q;
    q *= r;
  }
  pm[tid] = mu; ps[tid] = sg;
  __syncthreads();

  float lp = 0.f;
  if (qi == 0) {
    #pragma unroll
    for (int k = 1; k < 4; ++k) { mu += pm[tid + 128 * k]; sg += ps[tid + 128 * k]; }
    mu *= 0x1p-64f;                        // undo 2^64 scaling
    sg *= 0x1p-64f;
    out[b * NT + t]      = mu;
    out[BN + b * NT + t] = sg;
    float z = (yt[b * NT + t] - mu) / sg;
    lp = -0.5f * z * z - __logf(sg) - 0.5f * LN2PI;
  }
  #pragma unroll
  for (int m = 32; m; m >>= 1) lp += __shfl_xor(lp, m);
  if ((tid & 63) == 0) red[tid >> 6] = lp;
  __syncthreads();
  if (tid == 0) {
    float tot = 0.f;
    #pragma unroll
    for (int i = 0; i < 8; ++i) tot += red[i];
    atomicAdd(out + 2 * BN, -tot * (1.f / (float)NT));
  }
}

extern "C" void kernel_launch(void* const* d_in, const int* in_sizes, int n_in,
                              void* d_out, int out_size, void* d_ws, size_t ws_size,
                              hipStream_t stream) {
  const float* xc  = (const float*)d_in[0];
  const float* yc  = (const float*)d_in[1];
  const float* xt  = (const float*)d_in[2];
  const float* yt  = (const float*)d_in[3];
  const float* lsx = (const float*)d_in[4];
  const float* lsr = (const float*)d_in[5];
  const float* W1  = (const float*)d_in[6];  const float* b1 = (const float*)d_in[7];
  const float* W2  = (const float*)d_in[8];  const float* b2 = (const float*)d_in[9];
  const float* W3  = (const float*)d_in[10]; const float* b3 = (const float*)d_in[11];
  const float* W4  = (const float*)d_in[12]; const float* b4 = (const float*)d_in[13];

  float* out = (float*)d_out;
  float* h   = (float*)d_ws;        // B*2*G
  float* yg  = h + B * 2 * G;       // B*2*G

  k_smooth<<<dim3(16, B), 512, 0, stream>>>(xc, yc, lsx, h, out + 2 * BN);
  k_conv<<<dim3(NTILE, B), 256, 0, stream>>>(h, W1, b1, W2, b2, W3, b3, W4, b4, yg);
  k_pred<<<dim3(16, B), 512, 0, stream>>>(xt, yt, lsr, yg, out);
}